// Round 1
// baseline (973.092 us; speedup 1.0000x reference)
//
#include <hip/hip_runtime.h>
#include <math.h>

// Problem constants (GatedResidualCondConv)
#define NB   8
#define NR   128
#define NC   128
#define ND   128
#define NS   256
#define NT   16384
#define DILC 64
#define TTV  16320      // NT - DILC
#define TBW  32         // time tile per block
#define NTILE 510       // TTV / TBW

// ---------------------------------------------------------------------------
// Pack W1[256][384]: rows 0..127 = filt (d), 128..255 = gate (d)
// cols 0..127  -> w_*[d][r][0]  (vs x0)
// cols 128..255-> w_*[d][r][1]  (vs x1)
// cols 256..383-> w_p*[d][c]    (vs cond)
// ---------------------------------------------------------------------------
__global__ void pack_w1_kernel(const float* __restrict__ w_sig,
                               const float* __restrict__ w_gate,
                               const float* __restrict__ w_psig,
                               const float* __restrict__ w_pgate,
                               float* __restrict__ W1) {
    int idx = blockIdx.x * 256 + threadIdx.x;
    if (idx >= 256 * 384) return;
    int row = idx / 384;
    int k   = idx - row * 384;
    int d   = row & 127;
    const float* wa = (row < 128) ? w_sig  : w_gate;
    const float* wp = (row < 128) ? w_psig : w_pgate;
    float v;
    if (k < 128)      v = wa[d * 256 + k * 2 + 0];
    else if (k < 256) v = wa[d * 256 + (k - 128) * 2 + 1];
    else              v = wp[d * 128 + (k - 256)];
    W1[idx] = v;
}

// ---------------------------------------------------------------------------
// Phase-1 K-segment: acc[8 rows][4 cols] += W1-chunk * U-chunk (K=128)
// us points at LDS row 0, already offset by this thread's column (jl).
// w1a/w1b point at this thread's filt/gate row 0 for this K segment.
// ---------------------------------------------------------------------------
template<int USSTRIDE>
__device__ __forceinline__ void p1_seg(const float* __restrict__ us,
                                       const float* __restrict__ w1a,
                                       const float* __restrict__ w1b,
                                       float accF[4][4], float accG[4][4]) {
#pragma unroll 1
    for (int k = 0; k < 128; k += 4) {
        float u[4][4];
#pragma unroll
        for (int kk = 0; kk < 4; ++kk) {
            float4 t4 = *reinterpret_cast<const float4*>(us + (k + kk) * USSTRIDE);
            u[kk][0] = t4.x; u[kk][1] = t4.y; u[kk][2] = t4.z; u[kk][3] = t4.w;
        }
#pragma unroll
        for (int i = 0; i < 4; ++i) {
            float4 wf4 = *reinterpret_cast<const float4*>(w1a + i * 384 + k);
            float4 wg4 = *reinterpret_cast<const float4*>(w1b + i * 384 + k);
            float wf[4] = {wf4.x, wf4.y, wf4.z, wf4.w};
            float wg[4] = {wg4.x, wg4.y, wg4.z, wg4.w};
#pragma unroll
            for (int kk = 0; kk < 4; ++kk) {
#pragma unroll
                for (int j = 0; j < 4; ++j) {
                    accF[i][j] = fmaf(wf[kk], u[kk][j], accF[i][j]);
                    accG[i][j] = fmaf(wg[kk], u[kk][j], accG[i][j]);
                }
            }
        }
    }
}

// ---------------------------------------------------------------------------
// Fused kernel: one block = (batch b, 32 timesteps)
// ---------------------------------------------------------------------------
__global__ __launch_bounds__(256, 2)
void fused_kernel(const float* __restrict__ x, const float* __restrict__ cond,
                  const float* __restrict__ W1,
                  const float* __restrict__ b_sig, const float* __restrict__ b_gate,
                  const float* __restrict__ w_res, const float* __restrict__ w_skp,
                  float* __restrict__ out) {
    // xs[r][0..31]  = x[b][r][t0    .. t0+31]   (x0 tile)
    // xs[r][32..63] = x[b][r][t0+64 .. t0+95]   (x1 tile, also residual)
    __shared__ float xs[NR * 64];
    // csz: first used as cs[128][32] (c tile), then overwritten as zs[128][36]
    __shared__ float csz[ND * 36];

    const int tid = threadIdx.x;
    const int t0  = blockIdx.x * TBW;
    const int b   = blockIdx.y;

    // ---- stage x tile (2048 float4) ----
    {
        const float* xb = x + (size_t)b * NR * NT;
#pragma unroll
        for (int it = 0; it < 8; ++it) {
            int idx = it * 256 + tid;          // 0..2047
            int row = idx >> 4;                // 16 vec4 per row
            int v   = idx & 15;
            int sc  = (v < 8) ? (v * 4) : (v * 4 + 32);   // +64 src shift for x1 half
            float4 val = *reinterpret_cast<const float4*>(xb + (size_t)row * NT + t0 + sc);
            *reinterpret_cast<float4*>(&xs[row * 64 + v * 4]) = val;
        }
    }
    // ---- stage c tile (1024 float4), c[t] = cond[t + DIL] ----
    {
        const float* cb = cond + (size_t)b * NC * NT + DILC;
#pragma unroll
        for (int it = 0; it < 4; ++it) {
            int idx = it * 256 + tid;          // 0..1023
            int row = idx >> 3;
            int v   = idx & 7;
            float4 val = *reinterpret_cast<const float4*>(cb + (size_t)row * NT + t0 + v * 4);
            *reinterpret_cast<float4*>(&csz[row * 32 + v * 4]) = val;
        }
    }
    __syncthreads();

    const int rg = tid >> 3;     // 0..31 row group
    const int cg = tid & 7;      // 0..7  col group
    const int d0 = rg * 4;       // this thread's 4 filt/gate channels
    const int jl = cg * 4;       // this thread's 4 time columns

    // ---- phase 1: filt/gate = W1 @ [x0; x1; c] + bias ----
    float accF[4][4], accG[4][4];
#pragma unroll
    for (int i = 0; i < 4; ++i) {
        float bf = b_sig[d0 + i], bg = b_gate[d0 + i];
#pragma unroll
        for (int j = 0; j < 4; ++j) { accF[i][j] = bf; accG[i][j] = bg; }
    }

    p1_seg<64>(&xs[jl],      W1 + (size_t)d0 * 384,             W1 + (size_t)(128 + d0) * 384,       accF, accG); // x0
    p1_seg<64>(&xs[32 + jl], W1 + (size_t)d0 * 384 + 128,       W1 + (size_t)(128 + d0) * 384 + 128, accF, accG); // x1
    p1_seg<32>(&csz[jl],     W1 + (size_t)d0 * 384 + 256,       W1 + (size_t)(128 + d0) * 384 + 256, accF, accG); // c

    __syncthreads();   // everyone done reading cs before z overwrites it

    // ---- z = tanh(filt) * sigmoid(gate), write to zs[128][36] ----
#pragma unroll
    for (int i = 0; i < 4; ++i) {
        float4 zv;
        float z0 = tanhf(accF[i][0]) * (1.0f / (1.0f + __expf(-accG[i][0])));
        float z1 = tanhf(accF[i][1]) * (1.0f / (1.0f + __expf(-accG[i][1])));
        float z2 = tanhf(accF[i][2]) * (1.0f / (1.0f + __expf(-accG[i][2])));
        float z3 = tanhf(accF[i][3]) * (1.0f / (1.0f + __expf(-accG[i][3])));
        zv.x = z0; zv.y = z1; zv.z = z2; zv.w = z3;
        *reinterpret_cast<float4*>(&csz[(d0 + i) * 36 + jl]) = zv;
    }
    __syncthreads();

    // ---- phase 2: sig = w_res @ z + x1 ; skp = w_skp @ z ----
    const int r0 = rg * 4;   // 4 sig rows
    const int s0 = rg * 8;   // 8 skp rows
    float accS[4][4], accK[8][4];
#pragma unroll
    for (int i = 0; i < 4; ++i)
#pragma unroll
        for (int j = 0; j < 4; ++j) accS[i][j] = 0.0f;
#pragma unroll
    for (int i = 0; i < 8; ++i)
#pragma unroll
        for (int j = 0; j < 4; ++j) accK[i][j] = 0.0f;

#pragma unroll 1
    for (int k = 0; k < 128; k += 4) {
        float u[4][4];
#pragma unroll
        for (int kk = 0; kk < 4; ++kk) {
            float4 t4 = *reinterpret_cast<const float4*>(&csz[(k + kk) * 36 + jl]);
            u[kk][0] = t4.x; u[kk][1] = t4.y; u[kk][2] = t4.z; u[kk][3] = t4.w;
        }
#pragma unroll
        for (int i = 0; i < 4; ++i) {
            float4 w4 = *reinterpret_cast<const float4*>(&w_res[(size_t)(r0 + i) * 128 + k]);
            float w[4] = {w4.x, w4.y, w4.z, w4.w};
#pragma unroll
            for (int kk = 0; kk < 4; ++kk)
#pragma unroll
                for (int j = 0; j < 4; ++j)
                    accS[i][j] = fmaf(w[kk], u[kk][j], accS[i][j]);
        }
#pragma unroll
        for (int i = 0; i < 8; ++i) {
            float4 w4 = *reinterpret_cast<const float4*>(&w_skp[(size_t)(s0 + i) * 128 + k]);
            float w[4] = {w4.x, w4.y, w4.z, w4.w};
#pragma unroll
            for (int kk = 0; kk < 4; ++kk)
#pragma unroll
                for (int j = 0; j < 4; ++j)
                    accK[i][j] = fmaf(w[kk], u[kk][j], accK[i][j]);
        }
    }

    // ---- epilogue: sig += x1, store both outputs (float4, coalesced) ----
    float* sig_out = out + (size_t)b * NR * TTV;
    float* skp_out = out + (size_t)NB * NR * TTV + (size_t)b * NS * TTV;

#pragma unroll
    for (int i = 0; i < 4; ++i) {
        float4 xv = *reinterpret_cast<const float4*>(&xs[(r0 + i) * 64 + 32 + jl]);
        float4 o;
        o.x = accS[i][0] + xv.x;
        o.y = accS[i][1] + xv.y;
        o.z = accS[i][2] + xv.z;
        o.w = accS[i][3] + xv.w;
        *reinterpret_cast<float4*>(&sig_out[(size_t)(r0 + i) * TTV + t0 + jl]) = o;
    }
#pragma unroll
    for (int i = 0; i < 8; ++i) {
        float4 o;
        o.x = accK[i][0]; o.y = accK[i][1]; o.z = accK[i][2]; o.w = accK[i][3];
        *reinterpret_cast<float4*>(&skp_out[(size_t)(s0 + i) * TTV + t0 + jl]) = o;
    }
}

// ---------------------------------------------------------------------------
extern "C" void kernel_launch(void* const* d_in, const int* in_sizes, int n_in,
                              void* d_out, int out_size, void* d_ws, size_t ws_size,
                              hipStream_t stream) {
    const float* x       = (const float*)d_in[0];
    const float* cond    = (const float*)d_in[1];
    const float* w_sig   = (const float*)d_in[2];
    const float* b_sig   = (const float*)d_in[3];
    const float* w_gate  = (const float*)d_in[4];
    const float* b_gate  = (const float*)d_in[5];
    const float* w_psig  = (const float*)d_in[6];
    const float* w_pgate = (const float*)d_in[7];
    const float* w_res   = (const float*)d_in[8];
    const float* w_skp   = (const float*)d_in[9];
    float* out = (float*)d_out;
    float* W1  = (float*)d_ws;     // 256*384 floats = 384 KB

    if (ws_size < (size_t)256 * 384 * sizeof(float)) return;  // need repacked-W1 scratch

    pack_w1_kernel<<<384, 256, 0, stream>>>(w_sig, w_gate, w_psig, w_pgate, W1);

    dim3 grid(NTILE, NB);
    fused_kernel<<<grid, 256, 0, stream>>>(x, cond, W1, b_sig, b_gate, w_res, w_skp, out);
}

// Round 4
// 527.253 us; speedup vs baseline: 1.8456x; 1.8456x over previous
//
#include <hip/hip_runtime.h>
#include <math.h>

// Problem constants (GatedResidualCondConv)
#define NB   8
#define NR   128
#define NC   128
#define ND   128
#define NS   256
#define NT   16384
#define DILC 64
#define TTV  16320          // NT - DILC
#define TBW  48             // time tile per block (TTV = 48*340)
#define NTILE 340

typedef __attribute__((ext_vector_type(8))) short bf16x8;   // 8 bf16 (4 VGPRs)
typedef __attribute__((ext_vector_type(4))) float f32x4;    // MFMA C/D

typedef unsigned short ushort_t;
typedef unsigned int   uint_t;

// fp32 -> bf16 (RNE) bit trick
__device__ __forceinline__ ushort_t f2bf(float f) {
    uint_t u = __float_as_uint(f);
    u += 0x7FFFu + ((u >> 16) & 1u);
    return (ushort_t)(u >> 16);
}
__device__ __forceinline__ float bf2f(ushort_t h) {
    return __uint_as_float(((uint_t)h) << 16);
}

// LDS XOR swizzle: spreads 16-consecutive-t reads AND stride-4-t writes
#define SWZ(t) ((((t) ^ ((t) >> 2)) & 7) << 4)

// ---------------------------------------------------------------------------
// Pack W1 into frag-contiguous hi/lo planes.
// Packed rows: prow = 2d+g (g=0 filt/w_sig, g=1 gate/w_gate) -> z in-register.
// Frag f = ks*16 + m holds rows m*16..m*16+15, k = ks*32..ks*32+31.
// Within frag: elem = rr*32 + kk  (rr=row-in-tile, kk=k-in-step).
// k<128: w[d][k][0] (x0); 128<=k<256: w[d][k-128][1] (x1); else wp[d][k-256] (c)
// ---------------------------------------------------------------------------
__global__ void pack_w1(const float* __restrict__ w_sig, const float* __restrict__ w_gate,
                        const float* __restrict__ w_psig, const float* __restrict__ w_pgate,
                        ushort_t* __restrict__ Wh, ushort_t* __restrict__ Wl) {
    int idx = blockIdx.x * 256 + threadIdx.x;       // 0 .. 98303
    int frag = idx >> 9, e = idx & 511;
    int rr = e >> 5, kk = e & 31;
    int m = frag & 15, ks = frag >> 4;
    int prow = m * 16 + rr;
    int d = prow >> 1, g = prow & 1;
    int k = ks * 32 + kk;
    const float* wa = g ? w_gate : w_sig;
    const float* wp = g ? w_pgate : w_psig;
    float v;
    if (k < 128)      v = wa[d * 256 + k * 2 + 0];
    else if (k < 256) v = wa[d * 256 + (k - 128) * 2 + 1];
    else              v = wp[d * 128 + (k - 256)];
    ushort_t h = f2bf(v);
    Wh[idx] = h;
    Wl[idx] = f2bf(v - bf2f(h));
}

// ---------------------------------------------------------------------------
// Pack W2 (rows 0..127 = w_res, 128..383 = w_skp), frag f = m*4 + ks.
// ---------------------------------------------------------------------------
__global__ void pack_w2(const float* __restrict__ w_res, const float* __restrict__ w_skp,
                        ushort_t* __restrict__ Wh, ushort_t* __restrict__ Wl) {
    int idx = blockIdx.x * 256 + threadIdx.x;       // 0 .. 49151
    int frag = idx >> 9, e = idx & 511;
    int rr = e >> 5, kk = e & 31;
    int m = frag >> 2, ks = frag & 3;
    int row = m * 16 + rr;
    int k = ks * 32 + kk;
    float v = (row < 128) ? w_res[row * 128 + k] : w_skp[(row - 128) * 128 + k];
    ushort_t h = f2bf(v);
    Wh[idx] = h;
    Wl[idx] = f2bf(v - bf2f(h));
}

// ---------------------------------------------------------------------------
// Fused MFMA kernel. Block = (48 timesteps, 1 batch). 4 waves.
// Phase 1: [filt;gate](256x48) = W1(256x384) @ U(384x48), U=[x0;x1;c]
// Phase 2: [sig;skp](384x48)   = W2(384x128) @ z(128x48)
// hi/lo bf16 split, 3 MFMA passes -> ~fp32 accuracy.
// ---------------------------------------------------------------------------
__global__ __launch_bounds__(256, 2)
void fused_mfma(const float* __restrict__ x, const float* __restrict__ cond,
                const ushort_t* __restrict__ W1h, const ushort_t* __restrict__ W1l,
                const ushort_t* __restrict__ W2h, const ushort_t* __restrict__ W2l,
                const float* __restrict__ b_sig, const float* __restrict__ b_gate,
                float* __restrict__ out) {
    // xs[t 0..111][r 0..127]: x cols t0..t0+111 (x0 uses t<48, x1 uses t in [64,112))
    __shared__ ushort_t xsh[112 * 128];
    __shared__ ushort_t xsl[112 * 128];
    // cs[t 0..47][c 0..127]: cond cols t0+64..t0+111; overlaid by z after phase 1
    __shared__ ushort_t csh[48 * 128];
    __shared__ ushort_t csl[48 * 128];
    // total LDS = 80 KiB exactly -> 2 blocks/CU

    const int tid  = threadIdx.x;
    const int lane = tid & 63;
    const int w    = tid >> 6;          // wave 0..3
    const int t0   = blockIdx.x * TBW;
    const int b    = blockIdx.y;

    // ---- stage x (128 rows x 112 cols, fp32 -> bf16 hi/lo, transposed) ----
    {
        const float* xb = x + (size_t)b * NR * NT;
#pragma unroll
        for (int it = 0; it < 16; ++it) {
            int idx = it * 256 + tid;           // 128 rows * 32 c4 slots
            int r = idx >> 5, c4 = idx & 31;
            if (c4 < 28) {
                float4 v = *reinterpret_cast<const float4*>(xb + (size_t)r * NT + t0 + c4 * 4);
                float vv[4] = {v.x, v.y, v.z, v.w};
#pragma unroll
                for (int j = 0; j < 4; ++j) {
                    int tt = c4 * 4 + j;
                    ushort_t h = f2bf(vv[j]);
                    ushort_t l = f2bf(vv[j] - bf2f(h));
                    int byte = ((tt << 8) + (r << 1)) ^ SWZ(tt);
                    *(ushort_t*)((char*)xsh + byte) = h;
                    *(ushort_t*)((char*)xsl + byte) = l;
                }
            }
        }
    }
    // ---- stage c (128 rows x 48 cols, source offset +64) ----
    {
        const float* cb = cond + (size_t)b * NC * NT + DILC;
#pragma unroll
        for (int it = 0; it < 8; ++it) {
            int idx = it * 256 + tid;           // 128 rows * 16 c4 slots
            int r = idx >> 4, c4 = idx & 15;
            if (c4 < 12) {
                float4 v = *reinterpret_cast<const float4*>(cb + (size_t)r * NT + t0 + c4 * 4);
                float vv[4] = {v.x, v.y, v.z, v.w};
#pragma unroll
                for (int j = 0; j < 4; ++j) {
                    int tt = c4 * 4 + j;
                    ushort_t h = f2bf(vv[j]);
                    ushort_t l = f2bf(vv[j] - bf2f(h));
                    int byte = ((tt << 8) + (r << 1)) ^ SWZ(tt);
                    *(ushort_t*)((char*)csh + byte) = h;
                    *(ushort_t*)((char*)csl + byte) = l;
                }
            }
        }
    }
    __syncthreads();

    const int tcol = lane & 15;     // t within a 16-col N-tile  (B/D col)
    const int koct = lane >> 4;     // k-octet (A/B), row-quad (C/D)
    const int aoff = tcol * 32 + koct * 8;   // elem offset inside a 16x32 frag

    // ---- phase 1: acc[4 Mtiles][3 Ntiles], K = 384 (3 segs x 4 ksteps) ----
    f32x4 acc[4][3];
#pragma unroll
    for (int m = 0; m < 4; ++m)
#pragma unroll
        for (int n = 0; n < 3; ++n) acc[m][n] = (f32x4){0.f, 0.f, 0.f, 0.f};

#pragma unroll
    for (int seg = 0; seg < 3; ++seg) {
#pragma unroll
        for (int k2 = 0; k2 < 4; ++k2) {
            const int ks = seg * 4 + k2;
            bf16x8 ah[4], al[4];
#pragma unroll
            for (int m = 0; m < 4; ++m) {
                int f = ks * 16 + (w * 4 + m);
                ah[m] = *reinterpret_cast<const bf16x8*>(W1h + f * 512 + aoff);
                al[m] = *reinterpret_cast<const bf16x8*>(W1l + f * 512 + aoff);
            }
            bf16x8 bh[3], bl[3];
            const int kin = k2 * 32 + koct * 8;     // k within segment plane
            const ushort_t* ph = (seg == 2) ? csh : xsh;
            const ushort_t* pl = (seg == 2) ? csl : xsl;
            const int tadd = (seg == 1) ? 64 : 0;
#pragma unroll
            for (int n = 0; n < 3; ++n) {
                int t = n * 16 + tcol + tadd;
                int byte = ((t << 8) + (kin << 1)) ^ SWZ(t);
                bh[n] = *reinterpret_cast<const bf16x8*>((const char*)ph + byte);
                bl[n] = *reinterpret_cast<const bf16x8*>((const char*)pl + byte);
            }
#pragma unroll
            for (int m = 0; m < 4; ++m)
#pragma unroll
                for (int n = 0; n < 3; ++n) {
                    acc[m][n] = __builtin_amdgcn_mfma_f32_16x16x32_bf16(ah[m], bh[n], acc[m][n], 0, 0, 0);
                    acc[m][n] = __builtin_amdgcn_mfma_f32_16x16x32_bf16(ah[m], bl[n], acc[m][n], 0, 0, 0);
                    acc[m][n] = __builtin_amdgcn_mfma_f32_16x16x32_bf16(al[m], bh[n], acc[m][n], 0, 0, 0);
                }
        }
    }

    __syncthreads();    // all waves done reading cs before z overlays it

    // ---- z = tanh(filt+bs) * sigmoid(gate+bg), write over cs (hi/lo) ----
    // C/D: packed row = (w*4+m)*16 + koct*4 + q; prow=2d+g -> regs (0,1)=f/g of d0, (2,3)=f/g of d0+1
#pragma unroll
    for (int m = 0; m < 4; ++m) {
        int d0 = (w * 4 + m) * 8 + koct * 2;
        float bs0 = b_sig[d0], bg0 = b_gate[d0];
        float bs1 = b_sig[d0 + 1], bg1 = b_gate[d0 + 1];
#pragma unroll
        for (int n = 0; n < 3; ++n) {
            int t = n * 16 + tcol;
            float f0 = acc[m][n][0] + bs0, g0 = acc[m][n][1] + bg0;
            float f1 = acc[m][n][2] + bs1, g1 = acc[m][n][3] + bg1;
            float e0 = __expf(2.f * f0), e1 = __expf(2.f * f1);
            float th0 = 1.f - 2.f * __builtin_amdgcn_rcpf(e0 + 1.f);
            float th1 = 1.f - 2.f * __builtin_amdgcn_rcpf(e1 + 1.f);
            float sg0 = __builtin_amdgcn_rcpf(1.f + __expf(-g0));
            float sg1 = __builtin_amdgcn_rcpf(1.f + __expf(-g1));
            float z0 = th0 * sg0, z1 = th1 * sg1;
            ushort_t h0 = f2bf(z0), h1 = f2bf(z1);
            ushort_t l0 = f2bf(z0 - bf2f(h0)), l1 = f2bf(z1 - bf2f(h1));
            int byte = ((t << 8) + (d0 << 1)) ^ SWZ(t);     // d0 even -> b32 aligned
            *(uint_t*)((char*)csh + byte) = (uint_t)h0 | ((uint_t)h1 << 16);
            *(uint_t*)((char*)csl + byte) = (uint_t)l0 | ((uint_t)l1 << 16);
        }
    }
    __syncthreads();

    // ---- phase 2: acc2[6 Mtiles][3 Ntiles], K = 128 ----
    f32x4 acc2[6][3];
#pragma unroll
    for (int m = 0; m < 6; ++m)
#pragma unroll
        for (int n = 0; n < 3; ++n) acc2[m][n] = (f32x4){0.f, 0.f, 0.f, 0.f};

#pragma unroll
    for (int ks = 0; ks < 4; ++ks) {
        bf16x8 ah[6], al[6];
#pragma unroll
        for (int m = 0; m < 6; ++m) {
            int f = (w * 6 + m) * 4 + ks;
            ah[m] = *reinterpret_cast<const bf16x8*>(W2h + f * 512 + aoff);
            al[m] = *reinterpret_cast<const bf16x8*>(W2l + f * 512 + aoff);
        }
        bf16x8 bh[3], bl[3];
        const int kin = ks * 32 + koct * 8;
#pragma unroll
        for (int n = 0; n < 3; ++n) {
            int t = n * 16 + tcol;
            int byte = ((t << 8) + (kin << 1)) ^ SWZ(t);
            bh[n] = *reinterpret_cast<const bf16x8*>((const char*)csh + byte);
            bl[n] = *reinterpret_cast<const bf16x8*>((const char*)csl + byte);
        }
#pragma unroll
        for (int m = 0; m < 6; ++m)
#pragma unroll
            for (int n = 0; n < 3; ++n) {
                acc2[m][n] = __builtin_amdgcn_mfma_f32_16x16x32_bf16(ah[m], bh[n], acc2[m][n], 0, 0, 0);
                acc2[m][n] = __builtin_amdgcn_mfma_f32_16x16x32_bf16(ah[m], bl[n], acc2[m][n], 0, 0, 0);
                acc2[m][n] = __builtin_amdgcn_mfma_f32_16x16x32_bf16(al[m], bh[n], acc2[m][n], 0, 0, 0);
            }
    }

    // ---- epilogue: rows <128 -> sig (+x1 residual, fp32 from global), else skp ----
    const float* xres   = x + (size_t)b * NR * NT + t0 + DILC;
    float* sig_out = out + (size_t)b * NR * TTV + t0;
    float* skp_out = out + (size_t)NB * NR * TTV + (size_t)b * NS * TTV + t0;
#pragma unroll
    for (int m = 0; m < 6; ++m) {
        int prow = (w * 6 + m) * 16 + koct * 4;
#pragma unroll
        for (int n = 0; n < 3; ++n) {
            int t = n * 16 + tcol;
#pragma unroll
            for (int q = 0; q < 4; ++q) {
                int row = prow + q;
                float v = acc2[m][n][q];
                if (row < 128) {
                    v += xres[(size_t)row * NT + t];
                    sig_out[(size_t)row * TTV + t] = v;
                } else {
                    skp_out[(size_t)(row - 128) * TTV + t] = v;
                }
            }
        }
    }
}

// ---------------------------------------------------------------------------
extern "C" void kernel_launch(void* const* d_in, const int* in_sizes, int n_in,
                              void* d_out, int out_size, void* d_ws, size_t ws_size,
                              hipStream_t stream) {
    const float* x       = (const float*)d_in[0];
    const float* cond    = (const float*)d_in[1];
    const float* w_sig   = (const float*)d_in[2];
    const float* b_sig   = (const float*)d_in[3];
    const float* w_gate  = (const float*)d_in[4];
    const float* b_gate  = (const float*)d_in[5];
    const float* w_psig  = (const float*)d_in[6];
    const float* w_pgate = (const float*)d_in[7];
    const float* w_res   = (const float*)d_in[8];
    const float* w_skp   = (const float*)d_in[9];
    float* out = (float*)d_out;

    // workspace layout: W1h[98304] W1l[98304] W2h[49152] W2l[49152] ushorts
    ushort_t* W1h = (ushort_t*)d_ws;
    ushort_t* W1l = W1h + 98304;
    ushort_t* W2h = W1l + 98304;
    ushort_t* W2l = W2h + 49152;
    if (ws_size < (size_t)(2 * (98304 + 49152)) * sizeof(ushort_t)) return;

    pack_w1<<<384, 256, 0, stream>>>(w_sig, w_gate, w_psig, w_pgate, W1h, W1l);
    pack_w2<<<192, 256, 0, stream>>>(w_res, w_skp, W2h, W2l);

    dim3 grid(NTILE, NB);
    fused_mfma<<<grid, 256, 0, stream>>>(x, cond, W1h, W1l, W2h, W2l, b_sig, b_gate, out);
}

// Round 6
// 465.075 us; speedup vs baseline: 2.0923x; 1.1337x over previous
//
#include <hip/hip_runtime.h>
#include <math.h>

// Problem constants (GatedResidualCondConv)
#define NB   8
#define NR   128
#define NC   128
#define ND   128
#define NS   256
#define NT   16384
#define DILC 64
#define TTV  16320          // NT - DILC
#define TBW  32             // time tile per block (TTV = 32*510)
#define NTILE 510

typedef __attribute__((ext_vector_type(8))) short bf16x8;   // 8 bf16 (4 VGPRs)
typedef __attribute__((ext_vector_type(4))) float f32x4;    // MFMA C/D

typedef unsigned short ushort_t;
typedef unsigned int   uint_t;

// fp32 -> bf16 (RNE) bit trick
__device__ __forceinline__ ushort_t f2bf(float f) {
    uint_t u = __float_as_uint(f);
    u += 0x7FFFu + ((u >> 16) & 1u);
    return (ushort_t)(u >> 16);
}
__device__ __forceinline__ float bf2f(ushort_t h) {
    return __uint_as_float(((uint_t)h) << 16);
}

// LDS XOR swizzle on the stored-column index
#define SWZ(t) ((((t) ^ ((t) >> 2)) & 7) << 4)

// ---------------------------------------------------------------------------
// Pack W1 into frag-contiguous hi/lo planes.
// Packed rows: prow = 2d+g (g=0 filt, g=1 gate). Frag f = ks*16 + m.
// ---------------------------------------------------------------------------
__global__ void pack_w1(const float* __restrict__ w_sig, const float* __restrict__ w_gate,
                        const float* __restrict__ w_psig, const float* __restrict__ w_pgate,
                        ushort_t* __restrict__ Wh, ushort_t* __restrict__ Wl) {
    int idx = blockIdx.x * 256 + threadIdx.x;       // 0 .. 98303
    int frag = idx >> 9, e = idx & 511;
    int rr = e >> 5, kk = e & 31;
    int m = frag & 15, ks = frag >> 4;
    int prow = m * 16 + rr;
    int d = prow >> 1, g = prow & 1;
    int k = ks * 32 + kk;
    const float* wa = g ? w_gate : w_sig;
    const float* wp = g ? w_pgate : w_psig;
    float v;
    if (k < 128)      v = wa[d * 256 + k * 2 + 0];
    else if (k < 256) v = wa[d * 256 + (k - 128) * 2 + 1];
    else              v = wp[d * 128 + (k - 256)];
    ushort_t h = f2bf(v);
    Wh[idx] = h;
    Wl[idx] = f2bf(v - bf2f(h));
}

// Pack W2 (rows 0..127 = w_res, 128..383 = w_skp), frag f = m*4 + ks.
__global__ void pack_w2(const float* __restrict__ w_res, const float* __restrict__ w_skp,
                        ushort_t* __restrict__ Wh, ushort_t* __restrict__ Wl) {
    int idx = blockIdx.x * 256 + threadIdx.x;       // 0 .. 49151
    int frag = idx >> 9, e = idx & 511;
    int rr = e >> 5, kk = e & 31;
    int m = frag >> 2, ks = frag & 3;
    int row = m * 16 + rr;
    int k = ks * 32 + kk;
    float v = (row < 128) ? w_res[row * 128 + k] : w_skp[(row - 128) * 128 + k];
    ushort_t h = f2bf(v);
    Wh[idx] = h;
    Wl[idx] = f2bf(v - bf2f(h));
}

// ---------------------------------------------------------------------------
// Fused MFMA kernel. Block = (1 batch, 32 timesteps). 4 waves. 48 KiB LDS.
// xs stored cols: c<32 -> x0 t=t0+c ; c>=32 -> x1 t=t0+32+c (i.e. t0+64..95)
// ---------------------------------------------------------------------------
__global__ __launch_bounds__(256, 3)
void fused_mfma(const float* __restrict__ x, const float* __restrict__ cond,
                const ushort_t* __restrict__ W1h, const ushort_t* __restrict__ W1l,
                const ushort_t* __restrict__ W2h, const ushort_t* __restrict__ W2l,
                const float* __restrict__ b_sig, const float* __restrict__ b_gate,
                float* __restrict__ out) {
    __shared__ ushort_t xsh[64 * 128];   // 16 KiB
    __shared__ ushort_t xsl[64 * 128];   // 16 KiB
    __shared__ ushort_t csh[32 * 128];   //  8 KiB  (cond, later z)
    __shared__ ushort_t csl[32 * 128];   //  8 KiB

    const int tid  = threadIdx.x;
    const int lane = tid & 63;
    const int w    = tid >> 6;          // wave 0..3

    // XCD-aware decode: grid.x = 4080 = 8 * 510 exactly.
    // dispatch slot s -> XCD ~ s&7; give each XCD one batch, sequential tiles.
    const int s    = blockIdx.x;
    const int b    = s & 7;
    const int tile = s >> 3;
    const int t0   = tile * TBW;

    // ---- stage x (128 rows x 64 stored cols, fp32 -> bf16 hi/lo) ----
    {
        const float* xb = x + (size_t)b * NR * NT;
#pragma unroll
        for (int it = 0; it < 8; ++it) {
            int idx = it * 256 + tid;           // 0..2047 = 128 rows * 16 c4 slots
            int r = idx >> 4, c4 = idx & 15;
            int gcol = (c4 < 8) ? c4 * 4 : c4 * 4 + 32;
            float4 v = *reinterpret_cast<const float4*>(xb + (size_t)r * NT + t0 + gcol);
            float vv[4] = {v.x, v.y, v.z, v.w};
#pragma unroll
            for (int j = 0; j < 4; ++j) {
                int c = c4 * 4 + j;
                ushort_t h = f2bf(vv[j]);
                ushort_t l = f2bf(vv[j] - bf2f(h));
                int byte = ((c << 8) + (r << 1)) ^ SWZ(c);
                *(ushort_t*)((char*)xsh + byte) = h;
                *(ushort_t*)((char*)xsl + byte) = l;
            }
        }
    }
    // ---- stage c (128 rows x 32 cols, source offset +64) ----
    {
        const float* cb = cond + (size_t)b * NC * NT + DILC;
#pragma unroll
        for (int it = 0; it < 4; ++it) {
            int idx = it * 256 + tid;           // 0..1023 = 128 rows * 8 c4 slots
            int r = idx >> 3, c4 = idx & 7;
            float4 v = *reinterpret_cast<const float4*>(cb + (size_t)r * NT + t0 + c4 * 4);
            float vv[4] = {v.x, v.y, v.z, v.w};
#pragma unroll
            for (int j = 0; j < 4; ++j) {
                int c = c4 * 4 + j;
                ushort_t h = f2bf(vv[j]);
                ushort_t l = f2bf(vv[j] - bf2f(h));
                int byte = ((c << 8) + (r << 1)) ^ SWZ(c);
                *(ushort_t*)((char*)csh + byte) = h;
                *(ushort_t*)((char*)csl + byte) = l;
            }
        }
    }
    __syncthreads();

    const int tcol = lane & 15;     // B/D column within 16-wide N-tile
    const int koct = lane >> 4;     // A/B k-octet; C/D row-quad
    const int aoff = tcol * 32 + koct * 8;   // elem offset inside a 16x32 frag

    // ---- phase 1: acc[4 M][2 N], K = 384, 2-deep A-frag prefetch ----
    f32x4 acc[4][2];
#pragma unroll
    for (int m = 0; m < 4; ++m)
#pragma unroll
        for (int n = 0; n < 2; ++n) acc[m][n] = (f32x4){0.f, 0.f, 0.f, 0.f};

    bf16x8 pah[2][4], pal[2][4];
#define LOADA1(BUFI, KSV)                                                        \
    {                                                                            \
        _Pragma("unroll") for (int m_ = 0; m_ < 4; ++m_) {                       \
            int f_ = (KSV) * 16 + (w * 4 + m_);                                  \
            pah[BUFI][m_] = *reinterpret_cast<const bf16x8*>(W1h + f_ * 512 + aoff); \
            pal[BUFI][m_] = *reinterpret_cast<const bf16x8*>(W1l + f_ * 512 + aoff); \
        }                                                                        \
    }

    LOADA1(0, 0);
#pragma unroll
    for (int ks = 0; ks < 12; ++ks) {
        const int cur = ks & 1, nxt = cur ^ 1;
        if (ks < 11) LOADA1(nxt, ks + 1);       // prefetch next k-step's A
        const int seg = ks >> 2, k2 = ks & 3;   // seg 0:x0 1:x1 2:c
        const int kin = k2 * 32 + koct * 8;
        const ushort_t* ph = (seg == 2) ? csh : xsh;
        const ushort_t* pl = (seg == 2) ? csl : xsl;
        const int cbase = (seg == 1) ? 32 : 0;
        bf16x8 bh[2], bl[2];
#pragma unroll
        for (int n = 0; n < 2; ++n) {
            int c = cbase + n * 16 + tcol;
            int byte = ((c << 8) + (kin << 1)) ^ SWZ(c);
            bh[n] = *reinterpret_cast<const bf16x8*>((const char*)ph + byte);
            bl[n] = *reinterpret_cast<const bf16x8*>((const char*)pl + byte);
        }
#pragma unroll
        for (int m = 0; m < 4; ++m)
#pragma unroll
            for (int n = 0; n < 2; ++n) {
                acc[m][n] = __builtin_amdgcn_mfma_f32_16x16x32_bf16(pah[cur][m], bh[n], acc[m][n], 0, 0, 0);
                acc[m][n] = __builtin_amdgcn_mfma_f32_16x16x32_bf16(pah[cur][m], bl[n], acc[m][n], 0, 0, 0);
                acc[m][n] = __builtin_amdgcn_mfma_f32_16x16x32_bf16(pal[cur][m], bh[n], acc[m][n], 0, 0, 0);
            }
    }

    __syncthreads();    // all waves done reading cs before z overlays it

    // ---- z = tanh(filt+bs) * sigmoid(gate+bg), overlay into cs (hi/lo) ----
    // prow = (w*4+m)*16 + koct*4 + q; prow=2d+g -> regs (0,1)=f/g of d0, (2,3)=f/g of d0+1
#pragma unroll
    for (int m = 0; m < 4; ++m) {
        int d0 = (w * 4 + m) * 8 + koct * 2;
        float bs0 = b_sig[d0], bg0 = b_gate[d0];
        float bs1 = b_sig[d0 + 1], bg1 = b_gate[d0 + 1];
#pragma unroll
        for (int n = 0; n < 2; ++n) {
            int t = n * 16 + tcol;
            float f0 = acc[m][n][0] + bs0, g0 = acc[m][n][1] + bg0;
            float f1 = acc[m][n][2] + bs1, g1 = acc[m][n][3] + bg1;
            float e0 = __expf(2.f * f0), e1 = __expf(2.f * f1);
            float th0 = 1.f - 2.f * __builtin_amdgcn_rcpf(e0 + 1.f);
            float th1 = 1.f - 2.f * __builtin_amdgcn_rcpf(e1 + 1.f);
            float sg0 = __builtin_amdgcn_rcpf(1.f + __expf(-g0));
            float sg1 = __builtin_amdgcn_rcpf(1.f + __expf(-g1));
            float z0 = th0 * sg0, z1 = th1 * sg1;
            ushort_t h0 = f2bf(z0), h1 = f2bf(z1);
            ushort_t l0 = f2bf(z0 - bf2f(h0)), l1 = f2bf(z1 - bf2f(h1));
            int byte = ((t << 8) + (d0 << 1)) ^ SWZ(t);     // d0 even -> b32 aligned
            *(uint_t*)((char*)csh + byte) = (uint_t)h0 | ((uint_t)h1 << 16);
            *(uint_t*)((char*)csl + byte) = (uint_t)l0 | ((uint_t)l1 << 16);
        }
    }
    __syncthreads();

    // ---- phase 2 (m-outer, per-m epilogue, 2-deep A prefetch), K = 128 ----
    float* sig_out = out + (size_t)b * NR * TTV + t0;
    float* skp_out = out + (size_t)NB * NR * TTV + (size_t)b * NS * TTV + t0;

    bf16x8 qah[2][4], qal[2][4];
#define LOADA2(BUFI, MV)                                                         \
    {                                                                            \
        _Pragma("unroll") for (int ks_ = 0; ks_ < 4; ++ks_) {                    \
            int f_ = (w * 6 + (MV)) * 4 + ks_;                                   \
            qah[BUFI][ks_] = *reinterpret_cast<const bf16x8*>(W2h + f_ * 512 + aoff); \
            qal[BUFI][ks_] = *reinterpret_cast<const bf16x8*>(W2l + f_ * 512 + aoff); \
        }                                                                        \
    }

    LOADA2(0, 0);
#pragma unroll
    for (int m = 0; m < 6; ++m) {
        const int cur = m & 1, nxt = cur ^ 1;
        if (m < 5) LOADA2(nxt, m + 1);          // prefetch next m's A
        f32x4 a2[2];
        a2[0] = (f32x4){0.f, 0.f, 0.f, 0.f};
        a2[1] = (f32x4){0.f, 0.f, 0.f, 0.f};
#pragma unroll
        for (int ks = 0; ks < 4; ++ks) {
            const int kin = ks * 32 + koct * 8;
#pragma unroll
            for (int n = 0; n < 2; ++n) {
                int t = n * 16 + tcol;
                int byte = ((t << 8) + (kin << 1)) ^ SWZ(t);
                bf16x8 bh = *reinterpret_cast<const bf16x8*>((const char*)csh + byte);
                bf16x8 bl = *reinterpret_cast<const bf16x8*>((const char*)csl + byte);
                a2[n] = __builtin_amdgcn_mfma_f32_16x16x32_bf16(qah[cur][ks], bh, a2[n], 0, 0, 0);
                a2[n] = __builtin_amdgcn_mfma_f32_16x16x32_bf16(qah[cur][ks], bl, a2[n], 0, 0, 0);
                a2[n] = __builtin_amdgcn_mfma_f32_16x16x32_bf16(qal[cur][ks], bh, a2[n], 0, 0, 0);
            }
        }
        // per-m epilogue: row<128 <=> (w*6+m) < 8 (wave-uniform, folds at compile time)
        int prow = (w * 6 + m) * 16 + koct * 4;
#pragma unroll
        for (int n = 0; n < 2; ++n) {
            int t = n * 16 + tcol;
#pragma unroll
            for (int q = 0; q < 4; ++q) {
                int row = prow + q;
                float v = a2[n][q];
                if (w * 6 + m < 8) {
                    // sig: residual x1 reconstructed from LDS hi+lo (err ~2^-17 rel)
                    int c = 32 + t;
                    int byte = ((c << 8) + (row << 1)) ^ SWZ(c);
                    float x1v = bf2f(*(const ushort_t*)((const char*)xsh + byte))
                              + bf2f(*(const ushort_t*)((const char*)xsl + byte));
                    sig_out[(size_t)row * TTV + t] = v + x1v;
                } else {
                    skp_out[(size_t)(row - 128) * TTV + t] = v;
                }
            }
        }
    }
}

// ---------------------------------------------------------------------------
extern "C" void kernel_launch(void* const* d_in, const int* in_sizes, int n_in,
                              void* d_out, int out_size, void* d_ws, size_t ws_size,
                              hipStream_t stream) {
    const float* x       = (const float*)d_in[0];
    const float* cond    = (const float*)d_in[1];
    const float* w_sig   = (const float*)d_in[2];
    const float* b_sig   = (const float*)d_in[3];
    const float* w_gate  = (const float*)d_in[4];
    const float* b_gate  = (const float*)d_in[5];
    const float* w_psig  = (const float*)d_in[6];
    const float* w_pgate = (const float*)d_in[7];
    const float* w_res   = (const float*)d_in[8];
    const float* w_skp   = (const float*)d_in[9];
    float* out = (float*)d_out;

    // workspace layout: W1h[98304] W1l[98304] W2h[49152] W2l[49152] ushorts
    ushort_t* W1h = (ushort_t*)d_ws;
    ushort_t* W1l = W1h + 98304;
    ushort_t* W2h = W1l + 98304;
    ushort_t* W2l = W2h + 49152;
    if (ws_size < (size_t)(2 * (98304 + 49152)) * sizeof(ushort_t)) return;

    pack_w1<<<384, 256, 0, stream>>>(w_sig, w_gate, w_psig, w_pgate, W1h, W1l);
    pack_w2<<<192, 256, 0, stream>>>(w_res, w_skp, W2h, W2l);

    fused_mfma<<<NTILE * NB, 256, 0, stream>>>(x, cond, W1h, W1l, W2h, W2l, b_sig, b_gate, out);
}

// Round 7
// 460.938 us; speedup vs baseline: 2.1111x; 1.0090x over previous
//
#include <hip/hip_runtime.h>
#include <math.h>

// Problem constants (GatedResidualCondConv)
#define NB   8
#define NR   128
#define NC   128
#define ND   128
#define NS   256
#define NT   16384
#define DILC 64
#define TTV  16320          // NT - DILC
#define TBW  32             // time tile per block (TTV = 32*510)
#define NTILE 510

typedef __attribute__((ext_vector_type(8))) short bf16x8;   // 8 bf16 (4 VGPRs)
typedef __attribute__((ext_vector_type(4))) float f32x4;    // MFMA C/D

typedef unsigned short ushort_t;
typedef unsigned int   uint_t;

// fp32 -> bf16 (RNE) bit trick
__device__ __forceinline__ ushort_t f2bf(float f) {
    uint_t u = __float_as_uint(f);
    u += 0x7FFFu + ((u >> 16) & 1u);
    return (ushort_t)(u >> 16);
}
__device__ __forceinline__ float bf2f(ushort_t h) {
    return __uint_as_float(((uint_t)h) << 16);
}

// LDS XOR swizzle on the stored-column index
#define SWZ(t) ((((t) ^ ((t) >> 2)) & 7) << 4)

// ---------------------------------------------------------------------------
// Pack W1, hi/lo co-located: plane layout W1p[frag*1024 + plane*512 + e].
// Packed rows: prow = 2d+g (g=0 filt, g=1 gate). Frag f = ks*16 + m.
// Within frag: e = rr*32 + kk.
// ---------------------------------------------------------------------------
__global__ void pack_w1(const float* __restrict__ w_sig, const float* __restrict__ w_gate,
                        const float* __restrict__ w_psig, const float* __restrict__ w_pgate,
                        ushort_t* __restrict__ Wp) {
    int idx = blockIdx.x * 256 + threadIdx.x;       // 0 .. 98303
    int frag = idx >> 9, e = idx & 511;
    int rr = e >> 5, kk = e & 31;
    int m = frag & 15, ks = frag >> 4;
    int prow = m * 16 + rr;
    int d = prow >> 1, g = prow & 1;
    int k = ks * 32 + kk;
    const float* wa = g ? w_gate : w_sig;
    const float* wp = g ? w_pgate : w_psig;
    float v;
    if (k < 128)      v = wa[d * 256 + k * 2 + 0];
    else if (k < 256) v = wa[d * 256 + (k - 128) * 2 + 1];
    else              v = wp[d * 128 + (k - 256)];
    ushort_t h = f2bf(v);
    Wp[frag * 1024 + e]       = h;
    Wp[frag * 1024 + 512 + e] = f2bf(v - bf2f(h));
}

// Pack W2 (rows 0..127 = w_res, 128..383 = w_skp), frag f = m*4 + ks, co-located.
__global__ void pack_w2(const float* __restrict__ w_res, const float* __restrict__ w_skp,
                        ushort_t* __restrict__ Wp) {
    int idx = blockIdx.x * 256 + threadIdx.x;       // 0 .. 49151
    int frag = idx >> 9, e = idx & 511;
    int rr = e >> 5, kk = e & 31;
    int m = frag >> 2, ks = frag & 3;
    int row = m * 16 + rr;
    int k = ks * 32 + kk;
    float v = (row < 128) ? w_res[row * 128 + k] : w_skp[(row - 128) * 128 + k];
    ushort_t h = f2bf(v);
    Wp[frag * 1024 + e]       = h;
    Wp[frag * 1024 + 512 + e] = f2bf(v - bf2f(h));
}

// ---------------------------------------------------------------------------
// Fused MFMA kernel. Block = (1 batch, 32 timesteps). 4 waves. 48 KiB LDS.
// xs stored cols: c<32 -> x0 t=t0+c ; c>=32 -> x1 t=t0+32+c (i.e. t0+64..95)
// ---------------------------------------------------------------------------
__global__ __launch_bounds__(256, 3)
void fused_mfma(const float* __restrict__ x, const float* __restrict__ cond,
                const ushort_t* __restrict__ W1p, const ushort_t* __restrict__ W2p,
                const float* __restrict__ b_sig, const float* __restrict__ b_gate,
                float* __restrict__ out) {
    __shared__ ushort_t xsh[64 * 128];   // 16 KiB
    __shared__ ushort_t xsl[64 * 128];   // 16 KiB
    __shared__ ushort_t csh[32 * 128];   //  8 KiB  (cond, later z)
    __shared__ ushort_t csl[32 * 128];   //  8 KiB

    const int tid  = threadIdx.x;
    const int lane = tid & 63;
    const int w    = tid >> 6;          // wave 0..3

    // XCD-aware decode: grid.x = 4080 = 8 * 510 exactly.
    const int s    = blockIdx.x;
    const int b    = s & 7;
    const int tile = s >> 3;
    const int t0   = tile * TBW;

    // ---- stage x (128 rows x 64 stored cols), b32 row-pair LDS writes ----
    {
        const float* xb = x + (size_t)b * NR * NT;
#pragma unroll
        for (int it = 0; it < 4; ++it) {
            int idx = it * 256 + tid;           // 0..1023 = 64 rowpairs * 16 c4
            int r2 = idx >> 4, c4 = idx & 15;
            int gcol = (c4 < 8) ? c4 * 4 : c4 * 4 + 32;
            const float* rp = xb + (size_t)(2 * r2) * NT + t0 + gcol;
            float4 v0 = *reinterpret_cast<const float4*>(rp);
            float4 v1 = *reinterpret_cast<const float4*>(rp + NT);
            float a0[4] = {v0.x, v0.y, v0.z, v0.w};
            float a1[4] = {v1.x, v1.y, v1.z, v1.w};
#pragma unroll
            for (int j = 0; j < 4; ++j) {
                int c = c4 * 4 + j;
                ushort_t h0 = f2bf(a0[j]), h1 = f2bf(a1[j]);
                ushort_t l0 = f2bf(a0[j] - bf2f(h0)), l1 = f2bf(a1[j] - bf2f(h1));
                int byte = ((c << 8) + (r2 << 2)) ^ SWZ(c);
                *(uint_t*)((char*)xsh + byte) = (uint_t)h0 | ((uint_t)h1 << 16);
                *(uint_t*)((char*)xsl + byte) = (uint_t)l0 | ((uint_t)l1 << 16);
            }
        }
    }
    // ---- stage c (128 rows x 32 cols, source offset +64), b32 row-pairs ----
    {
        const float* cb = cond + (size_t)b * NC * NT + DILC;
#pragma unroll
        for (int it = 0; it < 2; ++it) {
            int idx = it * 256 + tid;           // 0..511 = 64 rowpairs * 8 c4
            int r2 = idx >> 3, c4 = idx & 7;
            const float* rp = cb + (size_t)(2 * r2) * NT + t0 + c4 * 4;
            float4 v0 = *reinterpret_cast<const float4*>(rp);
            float4 v1 = *reinterpret_cast<const float4*>(rp + NT);
            float a0[4] = {v0.x, v0.y, v0.z, v0.w};
            float a1[4] = {v1.x, v1.y, v1.z, v1.w};
#pragma unroll
            for (int j = 0; j < 4; ++j) {
                int c = c4 * 4 + j;
                ushort_t h0 = f2bf(a0[j]), h1 = f2bf(a1[j]);
                ushort_t l0 = f2bf(a0[j] - bf2f(h0)), l1 = f2bf(a1[j] - bf2f(h1));
                int byte = ((c << 8) + (r2 << 2)) ^ SWZ(c);
                *(uint_t*)((char*)csh + byte) = (uint_t)h0 | ((uint_t)h1 << 16);
                *(uint_t*)((char*)csl + byte) = (uint_t)l0 | ((uint_t)l1 << 16);
            }
        }
    }
    __syncthreads();

    const int tcol = lane & 15;     // B/D column within 16-wide N-tile
    const int koct = lane >> 4;     // A/B k-octet; C/D row-quad
    const int aoff = tcol * 32 + koct * 8;   // elem offset inside a 16x32 frag

    // ---- phase 1: acc[4 M][2 N], K = 384; ring-2 prefetch on A and B ----
    f32x4 acc[4][2];
#pragma unroll
    for (int m = 0; m < 4; ++m)
#pragma unroll
        for (int n = 0; n < 2; ++n) acc[m][n] = (f32x4){0.f, 0.f, 0.f, 0.f};

    bf16x8 pah[2][4], pal[2][4];      // A ring (hi/lo)
    bf16x8 pbh[2][2], pbl[2][2];      // B ring (hi/lo)

#define LOADA1(BUFI, KSV)                                                        \
    {                                                                            \
        _Pragma("unroll") for (int m_ = 0; m_ < 4; ++m_) {                       \
            const ushort_t* base_ = W1p + ((KSV) * 16 + (w * 4 + m_)) * 1024 + aoff; \
            pah[BUFI][m_] = *reinterpret_cast<const bf16x8*>(base_);             \
            pal[BUFI][m_] = *reinterpret_cast<const bf16x8*>(base_ + 512);       \
        }                                                                        \
    }
#define LOADB1(BUFI, KSV)                                                        \
    {                                                                            \
        const int seg_ = (KSV) >> 2, k2_ = (KSV) & 3;                            \
        const int kin_ = k2_ * 32 + koct * 8;                                    \
        const ushort_t* ph_ = (seg_ == 2) ? csh : xsh;                           \
        const ushort_t* pl_ = (seg_ == 2) ? csl : xsl;                           \
        const int cb_ = (seg_ == 1) ? 32 : 0;                                    \
        _Pragma("unroll") for (int n_ = 0; n_ < 2; ++n_) {                       \
            int c_ = cb_ + n_ * 16 + tcol;                                       \
            int byte_ = ((c_ << 8) + (kin_ << 1)) ^ SWZ(c_);                     \
            pbh[BUFI][n_] = *reinterpret_cast<const bf16x8*>((const char*)ph_ + byte_); \
            pbl[BUFI][n_] = *reinterpret_cast<const bf16x8*>((const char*)pl_ + byte_); \
        }                                                                        \
    }

    LOADA1(0, 0);
    LOADB1(0, 0);
#pragma unroll
    for (int ks = 0; ks < 12; ++ks) {
        const int cur = ks & 1, nxt = cur ^ 1;
        if (ks < 11) {
            LOADB1(nxt, ks + 1);        // LDS prefetch: next k-step's B
            LOADA1(nxt, ks + 1);        // global prefetch: next k-step's A
        }
#pragma unroll
        for (int m = 0; m < 4; ++m)
#pragma unroll
            for (int n = 0; n < 2; ++n) {
                acc[m][n] = __builtin_amdgcn_mfma_f32_16x16x32_bf16(pah[cur][m], pbh[cur][n], acc[m][n], 0, 0, 0);
                acc[m][n] = __builtin_amdgcn_mfma_f32_16x16x32_bf16(pah[cur][m], pbl[cur][n], acc[m][n], 0, 0, 0);
                acc[m][n] = __builtin_amdgcn_mfma_f32_16x16x32_bf16(pal[cur][m], pbh[cur][n], acc[m][n], 0, 0, 0);
            }
    }

    __syncthreads();    // all waves done reading cs before z overlays it

    // ---- z = tanh(filt+bs) * sigmoid(gate+bg), overlay into cs (hi/lo) ----
    // prow = (w*4+m)*16 + koct*4 + q; prow=2d+g -> regs (0,1)=f/g of d0, (2,3)=f/g of d0+1
#pragma unroll
    for (int m = 0; m < 4; ++m) {
        int d0 = (w * 4 + m) * 8 + koct * 2;
        float bs0 = b_sig[d0], bg0 = b_gate[d0];
        float bs1 = b_sig[d0 + 1], bg1 = b_gate[d0 + 1];
#pragma unroll
        for (int n = 0; n < 2; ++n) {
            int t = n * 16 + tcol;
            float f0 = acc[m][n][0] + bs0, g0 = acc[m][n][1] + bg0;
            float f1 = acc[m][n][2] + bs1, g1 = acc[m][n][3] + bg1;
            float e0 = __expf(2.f * f0), e1 = __expf(2.f * f1);
            float th0 = 1.f - 2.f * __builtin_amdgcn_rcpf(e0 + 1.f);
            float th1 = 1.f - 2.f * __builtin_amdgcn_rcpf(e1 + 1.f);
            float sg0 = __builtin_amdgcn_rcpf(1.f + __expf(-g0));
            float sg1 = __builtin_amdgcn_rcpf(1.f + __expf(-g1));
            float z0 = th0 * sg0, z1 = th1 * sg1;
            ushort_t h0 = f2bf(z0), h1 = f2bf(z1);
            ushort_t l0 = f2bf(z0 - bf2f(h0)), l1 = f2bf(z1 - bf2f(h1));
            int byte = ((t << 8) + (d0 << 1)) ^ SWZ(t);     // d0 even -> b32 aligned
            *(uint_t*)((char*)csh + byte) = (uint_t)h0 | ((uint_t)h1 << 16);
            *(uint_t*)((char*)csl + byte) = (uint_t)l0 | ((uint_t)l1 << 16);
        }
    }
    __syncthreads();

    // ---- phase 2: preload ALL z B-frags to registers (shared by all 6 m) ----
    bf16x8 zbh[4][2], zbl[4][2];      // 64 VGPR, reused by every m-tile
#pragma unroll
    for (int ks = 0; ks < 4; ++ks) {
        const int kin = ks * 32 + koct * 8;
#pragma unroll
        for (int n = 0; n < 2; ++n) {
            int t = n * 16 + tcol;
            int byte = ((t << 8) + (kin << 1)) ^ SWZ(t);
            zbh[ks][n] = *reinterpret_cast<const bf16x8*>((const char*)csh + byte);
            zbl[ks][n] = *reinterpret_cast<const bf16x8*>((const char*)csl + byte);
        }
    }

    float* sig_out = out + (size_t)b * NR * TTV + t0;
    float* skp_out = out + (size_t)NB * NR * TTV + (size_t)b * NS * TTV + t0;

    bf16x8 qah[2][4], qal[2][4];
#define LOADA2(BUFI, MV)                                                         \
    {                                                                            \
        _Pragma("unroll") for (int ks_ = 0; ks_ < 4; ++ks_) {                    \
            const ushort_t* base_ = W2p + ((w * 6 + (MV)) * 4 + ks_) * 1024 + aoff; \
            qah[BUFI][ks_] = *reinterpret_cast<const bf16x8*>(base_);            \
            qal[BUFI][ks_] = *reinterpret_cast<const bf16x8*>(base_ + 512);      \
        }                                                                        \
    }

    LOADA2(0, 0);
#pragma unroll
    for (int m = 0; m < 6; ++m) {
        const int cur = m & 1, nxt = cur ^ 1;
        if (m < 5) LOADA2(nxt, m + 1);          // prefetch next m's A
        f32x4 a2[2];
        a2[0] = (f32x4){0.f, 0.f, 0.f, 0.f};
        a2[1] = (f32x4){0.f, 0.f, 0.f, 0.f};
#pragma unroll
        for (int ks = 0; ks < 4; ++ks)
#pragma unroll
            for (int n = 0; n < 2; ++n) {
                a2[n] = __builtin_amdgcn_mfma_f32_16x16x32_bf16(qah[cur][ks], zbh[ks][n], a2[n], 0, 0, 0);
                a2[n] = __builtin_amdgcn_mfma_f32_16x16x32_bf16(qah[cur][ks], zbl[ks][n], a2[n], 0, 0, 0);
                a2[n] = __builtin_amdgcn_mfma_f32_16x16x32_bf16(qal[cur][ks], zbh[ks][n], a2[n], 0, 0, 0);
            }
        // per-m epilogue: row<128 <=> (w*6+m) < 8 (wave-uniform, folds at compile time)
        int prow = (w * 6 + m) * 16 + koct * 4;
#pragma unroll
        for (int n = 0; n < 2; ++n) {
            int t = n * 16 + tcol;
#pragma unroll
            for (int q = 0; q < 4; ++q) {
                int row = prow + q;
                float v = a2[n][q];
                if (w * 6 + m < 8) {
                    // sig: residual x1 reconstructed from LDS hi+lo (err ~2^-17 rel)
                    int c = 32 + t;
                    int byte = ((c << 8) + (row << 1)) ^ SWZ(c);
                    float x1v = bf2f(*(const ushort_t*)((const char*)xsh + byte))
                              + bf2f(*(const ushort_t*)((const char*)xsl + byte));
                    sig_out[(size_t)row * TTV + t] = v + x1v;
                } else {
                    skp_out[(size_t)(row - 128) * TTV + t] = v;
                }
            }
        }
    }
}

// ---------------------------------------------------------------------------
extern "C" void kernel_launch(void* const* d_in, const int* in_sizes, int n_in,
                              void* d_out, int out_size, void* d_ws, size_t ws_size,
                              hipStream_t stream) {
    const float* x       = (const float*)d_in[0];
    const float* cond    = (const float*)d_in[1];
    const float* w_sig   = (const float*)d_in[2];
    const float* b_sig   = (const float*)d_in[3];
    const float* w_gate  = (const float*)d_in[4];
    const float* b_gate  = (const float*)d_in[5];
    const float* w_psig  = (const float*)d_in[6];
    const float* w_pgate = (const float*)d_in[7];
    const float* w_res   = (const float*)d_in[8];
    const float* w_skp   = (const float*)d_in[9];
    float* out = (float*)d_out;

    // workspace layout: W1p[196608] W2p[98304] ushorts (hi/lo co-located)
    ushort_t* W1p = (ushort_t*)d_ws;
    ushort_t* W2p = W1p + 196608;
    if (ws_size < (size_t)(196608 + 98304) * sizeof(ushort_t)) return;

    pack_w1<<<384, 256, 0, stream>>>(w_sig, w_gate, w_psig, w_pgate, W1p);
    pack_w2<<<192, 256, 0, stream>>>(w_res, w_skp, W2p);

    fused_mfma<<<NTILE * NB, 256, 0, stream>>>(x, cond, W1p, W2p, b_sig, b_gate, out);
}

// Round 9
// 446.883 us; speedup vs baseline: 2.1775x; 1.0315x over previous
//
#include <hip/hip_runtime.h>
#include <hip/hip_bf16.h>
#include <math.h>

// Problem constants (GatedResidualCondConv)
#define NB   8
#define NR   128
#define NC   128
#define ND   128
#define NS   256
#define NT   16384
#define DILC 64
#define TTV  16320          // NT - DILC
#define TBW  32             // time tile per block (TTV = 32*510)
#define NTILE 510

typedef __attribute__((ext_vector_type(8))) short bf16x8;   // 8 bf16 (4 VGPRs)
typedef __attribute__((ext_vector_type(4))) float f32x4;    // MFMA C/D

typedef unsigned short ushort_t;
typedef unsigned int   uint_t;

// fp32 -> bf16 (RNE) bit trick (pack kernels; main kernel uses cvt_pk)
__device__ __forceinline__ ushort_t f2bf(float f) {
    uint_t u = __float_as_uint(f);
    u += 0x7FFFu + ((u >> 16) & 1u);
    return (ushort_t)(u >> 16);
}
__device__ __forceinline__ float bf2f(ushort_t h) {
    return __uint_as_float(((uint_t)h) << 16);
}
// packed pair: low short = bf16(a), high short = bf16(b)  (v_cvt_pk_bf16_f32)
__device__ __forceinline__ uint_t pk2(float a, float b) {
    __hip_bfloat162 h = __float22bfloat162_rn(float2{a, b});
    uint_t u;
    __builtin_memcpy(&u, &h, 4);
    return u;
}

// LDS XOR swizzle on the stored-column index (invariant to +32 on c)
#define SWZ(t) ((((t) ^ ((t) >> 2)) & 7) << 4)

// ---------------------------------------------------------------------------
// Pack W1, hi/lo co-located: W1p[frag*1024 + plane*512 + e].
// Packed rows: prow = 2d+g (g=0 filt, g=1 gate). Frag f = ks*16 + m.
// Within frag: e = rr*32 + kk.
// ---------------------------------------------------------------------------
__global__ void pack_w1(const float* __restrict__ w_sig, const float* __restrict__ w_gate,
                        const float* __restrict__ w_psig, const float* __restrict__ w_pgate,
                        ushort_t* __restrict__ Wp) {
    int idx = blockIdx.x * 256 + threadIdx.x;       // 0 .. 98303
    int frag = idx >> 9, e = idx & 511;
    int rr = e >> 5, kk = e & 31;
    int m = frag & 15, ks = frag >> 4;
    int prow = m * 16 + rr;
    int d = prow >> 1, g = prow & 1;
    int k = ks * 32 + kk;
    const float* wa = g ? w_gate : w_sig;
    const float* wp = g ? w_pgate : w_psig;
    float v;
    if (k < 128)      v = wa[d * 256 + k * 2 + 0];
    else if (k < 256) v = wa[d * 256 + (k - 128) * 2 + 1];
    else              v = wp[d * 128 + (k - 256)];
    ushort_t h = f2bf(v);
    Wp[frag * 1024 + e]       = h;
    Wp[frag * 1024 + 512 + e] = f2bf(v - bf2f(h));
}

// Pack W2 (rows 0..127 = w_res, 128..383 = w_skp), frag f = m*4 + ks, co-located.
__global__ void pack_w2(const float* __restrict__ w_res, const float* __restrict__ w_skp,
                        ushort_t* __restrict__ Wp) {
    int idx = blockIdx.x * 256 + threadIdx.x;       // 0 .. 49151
    int frag = idx >> 9, e = idx & 511;
    int rr = e >> 5, kk = e & 31;
    int m = frag >> 2, ks = frag & 3;
    int row = m * 16 + rr;
    int k = ks * 32 + kk;
    float v = (row < 128) ? w_res[row * 128 + k] : w_skp[(row - 128) * 128 + k];
    ushort_t h = f2bf(v);
    Wp[frag * 1024 + e]       = h;
    Wp[frag * 1024 + 512 + e] = f2bf(v - bf2f(h));
}

// ---------------------------------------------------------------------------
// Fused MFMA kernel, 2-pass hi/lo (weights split, inputs hi-only).
// Block = (1 batch, 32 timesteps). 4 waves. 32 KiB LDS.
// xs stored cols: c<32 -> x0 t=t0+c ; c>=32 -> x1 t=t0+32+c (i.e. t0+64..95)
// xl1: lo plane of the x1 half only (exact residual reconstruction).
// ---------------------------------------------------------------------------
__global__ __launch_bounds__(256, 4)
void fused_mfma(const float* __restrict__ x, const float* __restrict__ cond,
                const ushort_t* __restrict__ W1p, const ushort_t* __restrict__ W2p,
                const float* __restrict__ b_sig, const float* __restrict__ b_gate,
                float* __restrict__ out) {
    __shared__ ushort_t xsh[64 * 128];   // 16 KiB  (x hi, both halves)
    __shared__ ushort_t xl1[32 * 128];   //  8 KiB  (x1 lo, residual only)
    __shared__ ushort_t csh[32 * 128];   //  8 KiB  (cond hi, later z hi)

    const int tid  = threadIdx.x;
    const int lane = tid & 63;
    const int w    = tid >> 6;          // wave 0..3

    // XCD-aware decode: grid.x = 4080 = 8 * 510 exactly.
    const int s    = blockIdx.x;
    const int b    = s & 7;
    const int tile = s >> 3;
    const int t0   = tile * TBW;

    // ---- stage x (128 rows x 64 stored cols), b32 row-pair LDS writes ----
    {
        const float* xb = x + (size_t)b * NR * NT;
#pragma unroll
        for (int it = 0; it < 4; ++it) {
            int idx = it * 256 + tid;           // 0..1023 = 64 rowpairs * 16 c4
            int r2 = idx >> 4, c4 = idx & 15;
            int gcol = (c4 < 8) ? c4 * 4 : c4 * 4 + 32;
            const float* rp = xb + (size_t)(2 * r2) * NT + t0 + gcol;
            float4 v0 = *reinterpret_cast<const float4*>(rp);
            float4 v1 = *reinterpret_cast<const float4*>(rp + NT);
            float a0[4] = {v0.x, v0.y, v0.z, v0.w};
            float a1[4] = {v1.x, v1.y, v1.z, v1.w};
#pragma unroll
            for (int j = 0; j < 4; ++j) {
                int c = c4 * 4 + j;
                uint_t hp = pk2(a0[j], a1[j]);
                int byte = ((c << 8) + (r2 << 2)) ^ SWZ(c);
                *(uint_t*)((char*)xsh + byte) = hp;
                if (c4 >= 8) {      // x1 half: also store lo plane for residual
                    float l0 = a0[j] - __uint_as_float(hp << 16);
                    float l1 = a1[j] - __uint_as_float(hp & 0xffff0000u);
                    *(uint_t*)((char*)xl1 + byte - (32 << 8)) = pk2(l0, l1);
                }
            }
        }
    }
    // ---- stage c (128 rows x 32 cols, source offset +64), hi only ----
    {
        const float* cb = cond + (size_t)b * NC * NT + DILC;
#pragma unroll
        for (int it = 0; it < 2; ++it) {
            int idx = it * 256 + tid;           // 0..511 = 64 rowpairs * 8 c4
            int r2 = idx >> 3, c4 = idx & 7;
            const float* rp = cb + (size_t)(2 * r2) * NT + t0 + c4 * 4;
            float4 v0 = *reinterpret_cast<const float4*>(rp);
            float4 v1 = *reinterpret_cast<const float4*>(rp + NT);
            float a0[4] = {v0.x, v0.y, v0.z, v0.w};
            float a1[4] = {v1.x, v1.y, v1.z, v1.w};
#pragma unroll
            for (int j = 0; j < 4; ++j) {
                int c = c4 * 4 + j;
                int byte = ((c << 8) + (r2 << 2)) ^ SWZ(c);
                *(uint_t*)((char*)csh + byte) = pk2(a0[j], a1[j]);
            }
        }
    }
    __syncthreads();

    const int tcol = lane & 15;     // B/D column within 16-wide N-tile
    const int koct = lane >> 4;     // A/B k-octet; C/D row-quad
    const int aoff = tcol * 32 + koct * 8;   // elem offset inside a 16x32 frag

    // ---- phase 1: acc[4 M][2 N], K = 384, 2-pass (AhBh + AlBh) ----
    f32x4 acc[4][2];
#pragma unroll
    for (int m = 0; m < 4; ++m)
#pragma unroll
        for (int n = 0; n < 2; ++n) acc[m][n] = (f32x4){0.f, 0.f, 0.f, 0.f};

#pragma unroll
    for (int ks = 0; ks < 12; ++ks) {
        const int seg = ks >> 2, k2 = ks & 3;   // seg 0:x0 1:x1 2:c
        const int kin = k2 * 32 + koct * 8;
        const ushort_t* ph = (seg == 2) ? csh : xsh;
        const int cbase = (seg == 1) ? 32 : 0;
        bf16x8 bh[2];
#pragma unroll
        for (int n = 0; n < 2; ++n) {
            int c = cbase + n * 16 + tcol;
            int byte = ((c << 8) + (kin << 1)) ^ SWZ(c);
            bh[n] = *reinterpret_cast<const bf16x8*>((const char*)ph + byte);
        }
        bf16x8 ah[4], al[4];
#pragma unroll
        for (int m = 0; m < 4; ++m) {
            const ushort_t* base = W1p + (size_t)(ks * 16 + (w * 4 + m)) * 1024 + aoff;
            ah[m] = *reinterpret_cast<const bf16x8*>(base);
            al[m] = *reinterpret_cast<const bf16x8*>(base + 512);
        }
#pragma unroll
        for (int m = 0; m < 4; ++m)
#pragma unroll
            for (int n = 0; n < 2; ++n) {
                acc[m][n] = __builtin_amdgcn_mfma_f32_16x16x32_bf16(ah[m], bh[n], acc[m][n], 0, 0, 0);
                acc[m][n] = __builtin_amdgcn_mfma_f32_16x16x32_bf16(al[m], bh[n], acc[m][n], 0, 0, 0);
            }
    }

    __syncthreads();    // all waves done reading cs before z overlays it

    // ---- z = tanh(filt+bs) * sigmoid(gate+bg), overlay hi into cs ----
    // prow = (w*4+m)*16 + koct*4 + q; prow=2d+g -> regs (0,1)=f/g of d0, (2,3)=f/g of d0+1
#pragma unroll
    for (int m = 0; m < 4; ++m) {
        int d0 = (w * 4 + m) * 8 + koct * 2;
        float bs0 = b_sig[d0], bg0 = b_gate[d0];
        float bs1 = b_sig[d0 + 1], bg1 = b_gate[d0 + 1];
#pragma unroll
        for (int n = 0; n < 2; ++n) {
            int t = n * 16 + tcol;
            float f0 = acc[m][n][0] + bs0, g0 = acc[m][n][1] + bg0;
            float f1 = acc[m][n][2] + bs1, g1 = acc[m][n][3] + bg1;
            float e0 = __expf(2.f * f0), e1 = __expf(2.f * f1);
            float th0 = 1.f - 2.f * __builtin_amdgcn_rcpf(e0 + 1.f);
            float th1 = 1.f - 2.f * __builtin_amdgcn_rcpf(e1 + 1.f);
            float sg0 = __builtin_amdgcn_rcpf(1.f + __expf(-g0));
            float sg1 = __builtin_amdgcn_rcpf(1.f + __expf(-g1));
            float z0 = th0 * sg0, z1 = th1 * sg1;
            int byte = ((t << 8) + (d0 << 1)) ^ SWZ(t);     // d0 even -> b32 aligned
            *(uint_t*)((char*)csh + byte) = pk2(z0, z1);
        }
    }
    __syncthreads();

    // ---- phase 2: preload ALL z B-frags (reused by all 6 m-tiles) ----
    bf16x8 zb[4][2];      // 32 VGPR
#pragma unroll
    for (int ks = 0; ks < 4; ++ks) {
        const int kin = ks * 32 + koct * 8;
#pragma unroll
        for (int n = 0; n < 2; ++n) {
            int t = n * 16 + tcol;
            int byte = ((t << 8) + (kin << 1)) ^ SWZ(t);
            zb[ks][n] = *reinterpret_cast<const bf16x8*>((const char*)csh + byte);
        }
    }

    float* sig_out = out + (size_t)b * NR * TTV + t0;
    float* skp_out = out + (size_t)NB * NR * TTV + (size_t)b * NS * TTV + t0;

#pragma unroll
    for (int m = 0; m < 6; ++m) {
        bf16x8 qah[4], qal[4];
#pragma unroll
        for (int ks = 0; ks < 4; ++ks) {
            const ushort_t* base = W2p + (size_t)((w * 6 + m) * 4 + ks) * 1024 + aoff;
            qah[ks] = *reinterpret_cast<const bf16x8*>(base);
            qal[ks] = *reinterpret_cast<const bf16x8*>(base + 512);
        }
        f32x4 a2[2];
        a2[0] = (f32x4){0.f, 0.f, 0.f, 0.f};
        a2[1] = (f32x4){0.f, 0.f, 0.f, 0.f};
#pragma unroll
        for (int ks = 0; ks < 4; ++ks)
#pragma unroll
            for (int n = 0; n < 2; ++n) {
                a2[n] = __builtin_amdgcn_mfma_f32_16x16x32_bf16(qah[ks], zb[ks][n], a2[n], 0, 0, 0);
                a2[n] = __builtin_amdgcn_mfma_f32_16x16x32_bf16(qal[ks], zb[ks][n], a2[n], 0, 0, 0);
            }
        // per-m epilogue: row<128 <=> (w*6+m) < 8 (wave-uniform, folds at compile time)
        int prow = (w * 6 + m) * 16 + koct * 4;
#pragma unroll
        for (int n = 0; n < 2; ++n) {
            int t = n * 16 + tcol;
#pragma unroll
            for (int q = 0; q < 4; ++q) {
                int row = prow + q;
                float v = a2[n][q];
                if (w * 6 + m < 8) {
                    // sig: residual x1 = hi (xsh c=32+t) + lo (xl1 c'=t)
                    int c = 32 + t;
                    int byteh = ((c << 8) + (row << 1)) ^ SWZ(c);
                    int bytel = byteh - (32 << 8);
                    float x1v = bf2f(*(const ushort_t*)((const char*)xsh + byteh))
                              + bf2f(*(const ushort_t*)((const char*)xl1 + bytel));
                    sig_out[(size_t)row * TTV + t] = v + x1v;
                } else {
                    skp_out[(size_t)(row - 128) * TTV + t] = v;
                }
            }
        }
    }
}

// ---------------------------------------------------------------------------
extern "C" void kernel_launch(void* const* d_in, const int* in_sizes, int n_in,
                              void* d_out, int out_size, void* d_ws, size_t ws_size,
                              hipStream_t stream) {
    const float* x       = (const float*)d_in[0];
    const float* cond    = (const float*)d_in[1];
    const float* w_sig   = (const float*)d_in[2];
    const float* b_sig   = (const float*)d_in[3];
    const float* w_gate  = (const float*)d_in[4];
    const float* b_gate  = (const float*)d_in[5];
    const float* w_psig  = (const float*)d_in[6];
    const float* w_pgate = (const float*)d_in[7];
    const float* w_res   = (const float*)d_in[8];
    const float* w_skp   = (const float*)d_in[9];
    float* out = (float*)d_out;

    // workspace layout: W1p[196608] W2p[98304] ushorts (hi/lo co-located)
    ushort_t* W1p = (ushort_t*)d_ws;
    ushort_t* W2p = W1p + 196608;
    if (ws_size < (size_t)(196608 + 98304) * sizeof(ushort_t)) return;

    pack_w1<<<384, 256, 0, stream>>>(w_sig, w_gate, w_psig, w_pgate, W1p);
    pack_w2<<<192, 256, 0, stream>>>(w_res, w_skp, W2p);

    fused_mfma<<<NTILE * NB, 256, 0, stream>>>(x, cond, W1p, W2p, b_sig, b_gate, out);
}